// Round 1
// baseline (1337.600 us; speedup 1.0000x reference)
//
#include <hip/hip_runtime.h>
#include <hip/hip_bf16.h>
#include <cstdint>

typedef unsigned short u16;
typedef unsigned int u32;
typedef __attribute__((ext_vector_type(4))) float f32x4;
typedef __attribute__((ext_vector_type(8))) __bf16 bf16x8;

#define DEVFN static __device__ __forceinline__

constexpr int Bb = 4, S = 2048, Dm = 2048, H = 16, DH = 128;
constexpr int M  = Bb * S;   // 8192 rows
constexpr int N3 = 3 * Dm;   // 6144
constexpr float ATTN_SCALE = 0.088388347648318447f;  // 1/sqrt(128)
constexpr float LOG2E = 1.4426950408889634f;

DEVFN u16 f2bf(float f) {
  union { float f; u32 u; } v; v.f = f;
  u32 u = v.u;
  return (u16)((u + 0x7fffu + ((u >> 16) & 1u)) >> 16);
}

DEVFN void async16(const void* g, void* l) {
  __builtin_amdgcn_global_load_lds(
      (__attribute__((address_space(1))) unsigned int*)(g),
      (__attribute__((address_space(3))) unsigned int*)(l), 16, 0, 0);
}

// ---------------- prep kernels ----------------

__global__ __launch_bounds__(256) void k_cvt_bf16(const float* __restrict__ in,
                                                  u16* __restrict__ out, int n) {
  int i = (blockIdx.x * 256 + threadIdx.x) * 4;
  if (i < n) {
    float4 f = *(const float4*)(in + i);
    ushort4 o;
    o.x = f2bf(f.x); o.y = f2bf(f.y); o.z = f2bf(f.z); o.w = f2bf(f.w);
    *(ushort4*)(out + i) = o;
  }
}

// in: f32 [R][C] row-major -> out: bf16 [C][R] row-major
__global__ __launch_bounds__(256) void k_transpose_bf16(const float* __restrict__ in,
                                                        u16* __restrict__ out,
                                                        int R, int C) {
  __shared__ float tile[32][33];
  int c0 = blockIdx.x * 32, r0 = blockIdx.y * 32;
  int tx = threadIdx.x & 31, ty = threadIdx.x >> 5;  // 32 x 8
#pragma unroll
  for (int i = 0; i < 4; i++)
    tile[ty + 8 * i][tx] = in[(size_t)(r0 + ty + 8 * i) * C + c0 + tx];
  __syncthreads();
#pragma unroll
  for (int i = 0; i < 4; i++)
    out[(size_t)(c0 + ty + 8 * i) * R + r0 + tx] = f2bf(tile[tx][ty + 8 * i]);
}

// ---------------- GEMM: C = A[M,K](bf16) * BT[N,K](bf16)^T + bias ----------------
// MODE 0: plain f32 output Cf[M,N]
// MODE 1: qkv scatter epilogue (N==6144): q->q_bf(scaled), k->d_out+k_bf, v->d_out+v_bfT
template <int MODE>
__global__ __launch_bounds__(256) void k_gemm(
    const u16* __restrict__ A, const u16* __restrict__ BT,
    const float* __restrict__ bias, float* __restrict__ Cf,
    u16* __restrict__ q_bf, u16* __restrict__ k_bf, u16* __restrict__ v_bfT,
    int K, int N) {
  constexpr int BM = 128, BN = 128, BK = 32;
  __shared__ u16 ldsA[BM * BK];
  __shared__ u16 ldsB[BN * BK];
  const int tid = threadIdx.x;
  const int wid = tid >> 6, lane = tid & 63;
  const int wm = wid >> 1, wn = wid & 1;
  const int lrow = lane & 15, lkg = lane >> 4;
  const int tm0 = blockIdx.y * BM, tn0 = blockIdx.x * BN;

  f32x4 acc[4][4] = {};

  for (int k0 = 0; k0 < K; k0 += BK) {
    __syncthreads();  // protect LDS from previous iteration's readers
#pragma unroll
    for (int i = 0; i < 2; i++) {
      int t = i * 256 + tid;
      int row = t >> 2;            // 4 lanes per 64B row
      int cole = (t & 3) * 8;      // element offset in row
      const u16* ga = A + (size_t)(tm0 + row) * K + k0 + cole;
      char* la = (char*)ldsA + (size_t)(i * 256 + (tid & ~63)) * 16;
      async16(ga, la);
      const u16* gb = BT + (size_t)(tn0 + row) * K + k0 + cole;
      char* lb = (char*)ldsB + (size_t)(i * 256 + (tid & ~63)) * 16;
      async16(gb, lb);
    }
    __syncthreads();  // compiler drains vmcnt before barrier

    bf16x8 af[4], bfr[4];
#pragma unroll
    for (int mi = 0; mi < 4; mi++)
      af[mi] = *(const bf16x8*)(ldsA + (wm * 64 + mi * 16 + lrow) * BK + lkg * 8);
#pragma unroll
    for (int ni = 0; ni < 4; ni++)
      bfr[ni] = *(const bf16x8*)(ldsB + (wn * 64 + ni * 16 + lrow) * BK + lkg * 8);
#pragma unroll
    for (int mi = 0; mi < 4; mi++)
#pragma unroll
      for (int ni = 0; ni < 4; ni++)
        acc[mi][ni] = __builtin_amdgcn_mfma_f32_16x16x32_bf16(af[mi], bfr[ni],
                                                              acc[mi][ni], 0, 0, 0);
  }

  if (MODE == 0) {
#pragma unroll
    for (int mi = 0; mi < 4; mi++) {
      int row = tm0 + wm * 64 + mi * 16 + lkg * 4;
#pragma unroll
      for (int ni = 0; ni < 4; ni++) {
        int col = tn0 + wn * 64 + ni * 16 + lrow;
        float bv = bias[col];
#pragma unroll
        for (int r = 0; r < 4; r++)
          Cf[(size_t)(row + r) * N + col] = acc[mi][ni][r] + bv;
      }
    }
  } else {
#pragma unroll
    for (int mi = 0; mi < 4; mi++) {
      int row = tm0 + wm * 64 + mi * 16 + lkg * 4;
#pragma unroll
      for (int ni = 0; ni < 4; ni++) {
        int n = tn0 + wn * 64 + ni * 16 + lrow;
        float bv = bias[n];
        int type = n >> 11;      // 0:q 1:k 2:v
        int d = n & 2047;
        int h = d >> 7, dh = d & 127;
#pragma unroll
        for (int r = 0; r < 4; r++) {
          int rr = row + r;
          int b = rr >> 11, s = rr & 2047;
          float val = acc[mi][ni][r] + bv;
          size_t idx = ((size_t)(b * H + h) * S + s) * DH + dh;
          if (type == 0) {
            q_bf[idx] = f2bf(val * ATTN_SCALE);
          } else if (type == 1) {
            Cf[(size_t)M * Dm + idx] = val;      // k output (f32)
            k_bf[idx] = f2bf(val);
          } else {
            Cf[(size_t)2 * M * Dm + idx] = val;  // v output (f32)
            v_bfT[((size_t)(b * H + h) * DH + dh) * S + s] = f2bf(val);
          }
        }
      }
    }
  }
}

// ---------------- causal flash attention ----------------
// grid: (S/64, Bb*H); 4 waves x 16 q-rows. Q pre-scaled by 1/sqrt(DH).
__global__ __launch_bounds__(256) void k_attn(const u16* __restrict__ q_bf,
                                              const u16* __restrict__ k_bf,
                                              const u16* __restrict__ v_bfT,
                                              u16* __restrict__ attn_bf) {
  __shared__ u16 p_lds[4][16 * 32];
  const int tid = threadIdx.x;
  const int wid = tid >> 6, lane = tid & 63;
  const int lrow = lane & 15, lkg = lane >> 4;
  const int bh = blockIdx.y;
  const int b = bh >> 4, h = bh & 15;
  const int qr0 = blockIdx.x * 64 + wid * 16;

  const u16* qp = q_bf + (size_t)bh * S * DH;
  const u16* kp = k_bf + (size_t)bh * S * DH;
  const u16* vp = v_bfT + (size_t)bh * DH * S;

  bf16x8 qf[4];
#pragma unroll
  for (int kk = 0; kk < 4; kk++)
    qf[kk] = *(const bf16x8*)(qp + (size_t)(qr0 + lrow) * DH + kk * 32 + lkg * 8);

  float mr[4], lr[4];
#pragma unroll
  for (int r = 0; r < 4; r++) { mr[r] = -1e30f; lr[r] = 0.f; }
  f32x4 oacc[8] = {};

  const int row_base = qr0 + lkg * 4;
  const int nkb = (qr0 + 16 + 31) >> 5;  // k-blocks this wave needs

  for (int kb = 0; kb < nkb; kb++) {
    f32x4 sacc[2] = {};
#pragma unroll
    for (int kk = 0; kk < 4; kk++) {
      bf16x8 b0 = *(const bf16x8*)(kp + (size_t)(kb * 32 + lrow) * DH + kk * 32 + lkg * 8);
      bf16x8 b1 = *(const bf16x8*)(kp + (size_t)(kb * 32 + 16 + lrow) * DH + kk * 32 + lkg * 8);
      sacc[0] = __builtin_amdgcn_mfma_f32_16x16x32_bf16(qf[kk], b0, sacc[0], 0, 0, 0);
      sacc[1] = __builtin_amdgcn_mfma_f32_16x16x32_bf16(qf[kk], b1, sacc[1], 0, 0, 0);
    }
    // causal mask (only diagonal-straddling blocks)
    if (kb * 32 + 31 > qr0) {
#pragma unroll
      for (int nj = 0; nj < 2; nj++) {
        int col = kb * 32 + nj * 16 + lrow;
#pragma unroll
        for (int r = 0; r < 4; r++)
          if (col > row_base + r) sacc[nj][r] = -1e30f;
      }
    }
    // row max over 32 cols (16-lane groups hold one row each)
    float pm[4];
#pragma unroll
    for (int r = 0; r < 4; r++) pm[r] = fmaxf(sacc[0][r], sacc[1][r]);
#pragma unroll
    for (int off = 1; off < 16; off <<= 1)
#pragma unroll
      for (int r = 0; r < 4; r++) pm[r] = fmaxf(pm[r], __shfl_xor(pm[r], off, 64));

    float mnew[4], sc[4];
#pragma unroll
    for (int r = 0; r < 4; r++) {
      mnew[r] = fmaxf(mr[r], pm[r]);
      sc[r] = exp2f((mr[r] - mnew[r]) * LOG2E);
      mr[r] = mnew[r];
    }
    float rs[4] = {0.f, 0.f, 0.f, 0.f};
#pragma unroll
    for (int nj = 0; nj < 2; nj++)
#pragma unroll
      for (int r = 0; r < 4; r++) {
        float p = exp2f((sacc[nj][r] - mnew[r]) * LOG2E);
        rs[r] += p;
        p_lds[wid][(lkg * 4 + r) * 32 + nj * 16 + lrow] = f2bf(p);
      }
#pragma unroll
    for (int off = 1; off < 16; off <<= 1)
#pragma unroll
      for (int r = 0; r < 4; r++) rs[r] += __shfl_xor(rs[r], off, 64);
#pragma unroll
    for (int r = 0; r < 4; r++) lr[r] = lr[r] * sc[r] + rs[r];
#pragma unroll
    for (int nd = 0; nd < 8; nd++)
#pragma unroll
      for (int r = 0; r < 4; r++) oacc[nd][r] *= sc[r];

    asm volatile("s_waitcnt lgkmcnt(0)" ::: "memory");  // P write -> P read (same wave)
    bf16x8 pf = *(const bf16x8*)(&p_lds[wid][lrow * 32 + lkg * 8]);
#pragma unroll
    for (int nd = 0; nd < 8; nd++) {
      bf16x8 vf = *(const bf16x8*)(vp + (size_t)(nd * 16 + lrow) * S + kb * 32 + lkg * 8);
      oacc[nd] = __builtin_amdgcn_mfma_f32_16x16x32_bf16(pf, vf, oacc[nd], 0, 0, 0);
    }
  }

  float inv[4];
#pragma unroll
  for (int r = 0; r < 4; r++) inv[r] = 1.0f / lr[r];
#pragma unroll
  for (int nd = 0; nd < 8; nd++)
#pragma unroll
    for (int r = 0; r < 4; r++) {
      int rowg = row_base + r;  // s index
      size_t idx = ((size_t)(b * S + rowg) * H + h) * DH + nd * 16 + lrow;
      attn_bf[idx] = f2bf(oacc[nd][r] * inv[r]);
    }
}

// ---------------- launch ----------------

extern "C" void kernel_launch(void* const* d_in, const int* in_sizes, int n_in,
                              void* d_out, int out_size, void* d_ws, size_t ws_size,
                              hipStream_t stream) {
  const float* x     = (const float*)d_in[0];
  const float* w_qkv = (const float*)d_in[1];
  const float* b_qkv = (const float*)d_in[2];
  const float* w_out = (const float*)d_in[3];
  const float* b_out = (const float*)d_in[4];
  float* out = (float*)d_out;

  char* ws = (char*)d_ws;
  u16* x_bf    = (u16*)ws; ws += (size_t)M * Dm * 2;    // 33.5 MB
  u16* wqkvT   = (u16*)ws; ws += (size_t)N3 * Dm * 2;   // 25.2 MB
  u16* woutT   = (u16*)ws; ws += (size_t)Dm * Dm * 2;   //  8.4 MB
  u16* q_bf    = (u16*)ws; ws += (size_t)M * Dm * 2;
  u16* k_bf    = (u16*)ws; ws += (size_t)M * Dm * 2;
  u16* v_bfT   = (u16*)ws; ws += (size_t)M * Dm * 2;
  u16* attn_bf = (u16*)ws; ws += (size_t)M * Dm * 2;    // total ~192 MiB

  k_cvt_bf16<<<(M * Dm) / 1024, 256, 0, stream>>>(x, x_bf, M * Dm);
  k_transpose_bf16<<<dim3(N3 / 32, Dm / 32), 256, 0, stream>>>(w_qkv, wqkvT, Dm, N3);
  k_transpose_bf16<<<dim3(Dm / 32, Dm / 32), 256, 0, stream>>>(w_out, woutT, Dm, Dm);

  k_gemm<1><<<dim3(N3 / 128, M / 128), 256, 0, stream>>>(
      x_bf, wqkvT, b_qkv, out, q_bf, k_bf, v_bfT, Dm, N3);

  k_attn<<<dim3(S / 64, Bb * H), 256, 0, stream>>>(q_bf, k_bf, v_bfT, attn_bf);

  k_gemm<0><<<dim3(Dm / 128, M / 128), 256, 0, stream>>>(
      attn_bf, woutT, b_out, out, nullptr, nullptr, nullptr, Dm, Dm);
}

// Round 2
// 769.499 us; speedup vs baseline: 1.7383x; 1.7383x over previous
//
#include <hip/hip_runtime.h>
#include <hip/hip_bf16.h>
#include <cstdint>

typedef unsigned short u16;
typedef unsigned int u32;
typedef __attribute__((ext_vector_type(4))) float f32x4;
typedef __attribute__((ext_vector_type(8))) __bf16 bf16x8;

#define DEVFN static __device__ __forceinline__

constexpr int Bb = 4, S = 2048, Dm = 2048, H = 16, DH = 128;
constexpr int M  = Bb * S;   // 8192 rows
constexpr int N3 = 3 * Dm;   // 6144
constexpr float ATTN_SCALE = 0.088388347648318447f;  // 1/sqrt(128)
constexpr float LOG2E = 1.4426950408889634f;

DEVFN u16 f2bf(float f) {
  union { float f; u32 u; } v; v.f = f;
  u32 u = v.u;
  return (u16)((u + 0x7fffu + ((u >> 16) & 1u)) >> 16);
}

DEVFN void async16(const void* g, void* l) {
  __builtin_amdgcn_global_load_lds(
      (__attribute__((address_space(1))) unsigned int*)(g),
      (__attribute__((address_space(3))) unsigned int*)(l), 16, 0, 0);
}

// ---------------- prep kernels ----------------

__global__ __launch_bounds__(256) void k_cvt_bf16(const float* __restrict__ in,
                                                  u16* __restrict__ out, int n) {
  int i = (blockIdx.x * 256 + threadIdx.x) * 4;
  if (i < n) {
    float4 f = *(const float4*)(in + i);
    ushort4 o;
    o.x = f2bf(f.x); o.y = f2bf(f.y); o.z = f2bf(f.z); o.w = f2bf(f.w);
    *(ushort4*)(out + i) = o;
  }
}

// in: f32 [R][C] row-major -> out: bf16 [C][R] row-major
__global__ __launch_bounds__(256) void k_transpose_bf16(const float* __restrict__ in,
                                                        u16* __restrict__ out,
                                                        int R, int C) {
  __shared__ float tile[32][33];
  int c0 = blockIdx.x * 32, r0 = blockIdx.y * 32;
  int tx = threadIdx.x & 31, ty = threadIdx.x >> 5;  // 32 x 8
#pragma unroll
  for (int i = 0; i < 4; i++)
    tile[ty + 8 * i][tx] = in[(size_t)(r0 + ty + 8 * i) * C + c0 + tx];
  __syncthreads();
#pragma unroll
  for (int i = 0; i < 4; i++)
    out[(size_t)(c0 + ty + 8 * i) * R + r0 + tx] = f2bf(tile[tx][ty + 8 * i]);
}

// ---------------- GEMM: C = A[M,K](bf16) * BT[N,K](bf16)^T + bias ----------------
template <int MODE>
__global__ __launch_bounds__(256) void k_gemm(
    const u16* __restrict__ A, const u16* __restrict__ BT,
    const float* __restrict__ bias, float* __restrict__ Cf,
    u16* __restrict__ q_bf, u16* __restrict__ k_bf, u16* __restrict__ v_bfT,
    int K, int N) {
  constexpr int BM = 128, BN = 128, BK = 32;
  __shared__ u16 ldsA[BM * BK];
  __shared__ u16 ldsB[BN * BK];
  const int tid = threadIdx.x;
  const int wid = tid >> 6, lane = tid & 63;
  const int wm = wid >> 1, wn = wid & 1;
  const int lrow = lane & 15, lkg = lane >> 4;
  const int tm0 = blockIdx.y * BM, tn0 = blockIdx.x * BN;

  f32x4 acc[4][4] = {};

  for (int k0 = 0; k0 < K; k0 += BK) {
    __syncthreads();
#pragma unroll
    for (int i = 0; i < 2; i++) {
      int t = i * 256 + tid;
      int row = t >> 2;
      int cole = (t & 3) * 8;
      const u16* ga = A + (size_t)(tm0 + row) * K + k0 + cole;
      char* la = (char*)ldsA + (size_t)(i * 256 + (tid & ~63)) * 16;
      async16(ga, la);
      const u16* gb = BT + (size_t)(tn0 + row) * K + k0 + cole;
      char* lb = (char*)ldsB + (size_t)(i * 256 + (tid & ~63)) * 16;
      async16(gb, lb);
    }
    __syncthreads();

    bf16x8 af[4], bfr[4];
#pragma unroll
    for (int mi = 0; mi < 4; mi++)
      af[mi] = *(const bf16x8*)(ldsA + (wm * 64 + mi * 16 + lrow) * BK + lkg * 8);
#pragma unroll
    for (int ni = 0; ni < 4; ni++)
      bfr[ni] = *(const bf16x8*)(ldsB + (wn * 64 + ni * 16 + lrow) * BK + lkg * 8);
#pragma unroll
    for (int mi = 0; mi < 4; mi++)
#pragma unroll
      for (int ni = 0; ni < 4; ni++)
        acc[mi][ni] = __builtin_amdgcn_mfma_f32_16x16x32_bf16(af[mi], bfr[ni],
                                                              acc[mi][ni], 0, 0, 0);
  }

  if (MODE == 0) {
#pragma unroll
    for (int mi = 0; mi < 4; mi++) {
      int row = tm0 + wm * 64 + mi * 16 + lkg * 4;
#pragma unroll
      for (int ni = 0; ni < 4; ni++) {
        int col = tn0 + wn * 64 + ni * 16 + lrow;
        float bv = bias[col];
#pragma unroll
        for (int r = 0; r < 4; r++)
          Cf[(size_t)(row + r) * N + col] = acc[mi][ni][r] + bv;
      }
    }
  } else {
#pragma unroll
    for (int mi = 0; mi < 4; mi++) {
      int row = tm0 + wm * 64 + mi * 16 + lkg * 4;
#pragma unroll
      for (int ni = 0; ni < 4; ni++) {
        int n = tn0 + wn * 64 + ni * 16 + lrow;
        float bv = bias[n];
        int type = n >> 11;
        int d = n & 2047;
        int h = d >> 7, dh = d & 127;
#pragma unroll
        for (int r = 0; r < 4; r++) {
          int rr = row + r;
          int b = rr >> 11, s = rr & 2047;
          float val = acc[mi][ni][r] + bv;
          size_t idx = ((size_t)(b * H + h) * S + s) * DH + dh;
          if (type == 0) {
            q_bf[idx] = f2bf(val * ATTN_SCALE);
          } else if (type == 1) {
            Cf[(size_t)M * Dm + idx] = val;
            k_bf[idx] = f2bf(val);
          } else {
            Cf[(size_t)2 * M * Dm + idx] = val;
            v_bfT[((size_t)(b * H + h) * DH + dh) * S + s] = f2bf(val);
          }
        }
      }
    }
  }
}

// ---------------- causal flash attention v2 ----------------
// grid: (S/128, Bb*H); block = 4 waves, each wave owns 32 q-rows.
// K/V^T tiles (KVBLK=64) staged in LDS via global_load_lds with XOR-swizzled
// source (linear LDS dest) so swizzled ds_read_b128 is bank-conflict-free.
__global__ __launch_bounds__(256, 2) void k_attn(const u16* __restrict__ q_bf,
                                                 const u16* __restrict__ k_bf,
                                                 const u16* __restrict__ v_bfT,
                                                 u16* __restrict__ attn_bf) {
  __shared__ u16 ldsK[64 * 128];   // [k=64][d=128], 256B rows, swizzled
  __shared__ u16 ldsV[128 * 64];   // [d=128][k=64], 128B rows, swizzled
  __shared__ u16 ldsP[4][32 * 64]; // per-wave P tile [q=32][k=64], swizzled

  const int tid = threadIdx.x;
  const int wid = tid >> 6, lane = tid & 63;
  const int lrow = lane & 15, lkg = lane >> 4;
  const int bh = blockIdx.y;
  const int b = bh >> 4, h = bh & 15;
  const int qi = 15 - blockIdx.x;            // longest blocks dispatched first
  const int qb0 = qi * 128;
  const int wq0 = qb0 + wid * 32;
  const int swz = (lrow & 7) << 4;

  const u16* qp = q_bf + (size_t)bh * S * DH;
  const u16* kp = k_bf + (size_t)bh * S * DH;
  const u16* vp = v_bfT + (size_t)bh * DH * S;

  // Q fragments (pre-scaled): 32 rows x 128 dims
  bf16x8 qf[2][4];
#pragma unroll
  for (int qt = 0; qt < 2; qt++)
#pragma unroll
    for (int kk = 0; kk < 4; kk++)
      qf[qt][kk] = *(const bf16x8*)(qp + (size_t)(wq0 + qt * 16 + lrow) * DH +
                                    kk * 32 + lkg * 8);

  float mr[2][4], lr[2][4];
#pragma unroll
  for (int qt = 0; qt < 2; qt++)
#pragma unroll
    for (int r = 0; r < 4; r++) { mr[qt][r] = -1e30f; lr[qt][r] = 0.f; }
  f32x4 oacc[2][8] = {};

  const int nkb = qi * 2 + 2;

  for (int kb = 0; kb < nkb; kb++) {
    __syncthreads();  // previous tile's readers done
    // --- cooperative stage: K (16KB) + V^T (16KB), pre-swizzled source ---
#pragma unroll
    for (int i = 0; i < 4; i++) {
      int L = i * 4096 + wid * 1024 + lane * 16;
      int krow = L >> 8, kch = (L >> 4) & 15;
      async16(kp + (size_t)(kb * 64 + krow) * DH + ((kch ^ (krow & 7)) * 8),
              (char*)ldsK + L);
      int vd = L >> 7, vch = (L >> 4) & 7;
      async16(vp + (size_t)vd * S + kb * 64 + ((vch ^ (vd & 7)) * 8),
              (char*)ldsV + L);
    }
    __syncthreads();  // compiler drains vmcnt before barrier

    if (kb * 64 <= wq0 + 31) {  // wave has unmasked work in this k-block
      // --- QK^T: S[32q][64k] ---
      f32x4 sacc[2][4] = {};
#pragma unroll
      for (int kt = 0; kt < 4; kt++)
#pragma unroll
        for (int kk = 0; kk < 4; kk++) {
          bf16x8 kf = *(const bf16x8*)((const char*)ldsK +
                        (kt * 16 + lrow) * 256 + ((kk * 64 + lkg * 16) ^ swz));
          sacc[0][kt] = __builtin_amdgcn_mfma_f32_16x16x32_bf16(qf[0][kk], kf,
                                                                sacc[0][kt], 0, 0, 0);
          sacc[1][kt] = __builtin_amdgcn_mfma_f32_16x16x32_bf16(qf[1][kk], kf,
                                                                sacc[1][kt], 0, 0, 0);
        }

      // --- causal mask (diagonal-straddling blocks only) ---
      if (kb * 64 + 63 > wq0) {
#pragma unroll
        for (int qt = 0; qt < 2; qt++)
#pragma unroll
          for (int kt = 0; kt < 4; kt++) {
            int k = kb * 64 + kt * 16 + lrow;
#pragma unroll
            for (int r = 0; r < 4; r++)
              if (k > wq0 + qt * 16 + lkg * 4 + r) sacc[qt][kt][r] = -1e30f;
          }
      }

      // --- online softmax (row stats: in-lane over kt, shfl over 16 lanes) ---
      float pm[2][4];
#pragma unroll
      for (int qt = 0; qt < 2; qt++)
#pragma unroll
        for (int r = 0; r < 4; r++)
          pm[qt][r] = fmaxf(fmaxf(sacc[qt][0][r], sacc[qt][1][r]),
                            fmaxf(sacc[qt][2][r], sacc[qt][3][r]));
#pragma unroll
      for (int off = 1; off < 16; off <<= 1)
#pragma unroll
        for (int qt = 0; qt < 2; qt++)
#pragma unroll
          for (int r = 0; r < 4; r++)
            pm[qt][r] = fmaxf(pm[qt][r], __shfl_xor(pm[qt][r], off, 64));

      float sc[2][4];
#pragma unroll
      for (int qt = 0; qt < 2; qt++)
#pragma unroll
        for (int r = 0; r < 4; r++) {
          float mn = fmaxf(mr[qt][r], pm[qt][r]);
          sc[qt][r] = exp2f((mr[qt][r] - mn) * LOG2E);
          mr[qt][r] = mn;
        }

      float rs[2][4] = {};
#pragma unroll
      for (int qt = 0; qt < 2; qt++)
#pragma unroll
        for (int kt = 0; kt < 4; kt++)
#pragma unroll
          for (int r = 0; r < 4; r++) {
            float p = exp2f((sacc[qt][kt][r] - mr[qt][r]) * LOG2E);
            rs[qt][r] += p;
            int prow = qt * 16 + lkg * 4 + r;
            *(u16*)((char*)ldsP[wid] + prow * 128 +
                    (((kt * 16 + lrow) * 2) ^ ((prow & 7) << 4))) = f2bf(p);
          }
#pragma unroll
      for (int off = 1; off < 16; off <<= 1)
#pragma unroll
        for (int qt = 0; qt < 2; qt++)
#pragma unroll
          for (int r = 0; r < 4; r++)
            rs[qt][r] += __shfl_xor(rs[qt][r], off, 64);
#pragma unroll
      for (int qt = 0; qt < 2; qt++)
#pragma unroll
        for (int r = 0; r < 4; r++)
          lr[qt][r] = lr[qt][r] * sc[qt][r] + rs[qt][r];
#pragma unroll
      for (int qt = 0; qt < 2; qt++)
#pragma unroll
        for (int nd = 0; nd < 8; nd++)
#pragma unroll
          for (int r = 0; r < 4; r++) oacc[qt][nd][r] *= sc[qt][r];

      // --- PV: O += P[32q][64k] * V[64k][128d] ---
      asm volatile("s_waitcnt lgkmcnt(0)" ::: "memory");  // P write -> P read
      bf16x8 pf[2][2];
#pragma unroll
      for (int qt = 0; qt < 2; qt++)
#pragma unroll
        for (int kk = 0; kk < 2; kk++)
          pf[qt][kk] = *(const bf16x8*)((const char*)ldsP[wid] +
                         (qt * 16 + lrow) * 128 + ((kk * 64 + lkg * 16) ^ swz));
#pragma unroll
      for (int nd = 0; nd < 8; nd++) {
        bf16x8 vf0 = *(const bf16x8*)((const char*)ldsV +
                       (nd * 16 + lrow) * 128 + ((lkg * 16) ^ swz));
        bf16x8 vf1 = *(const bf16x8*)((const char*)ldsV +
                       (nd * 16 + lrow) * 128 + ((64 + lkg * 16) ^ swz));
#pragma unroll
        for (int qt = 0; qt < 2; qt++) {
          oacc[qt][nd] = __builtin_amdgcn_mfma_f32_16x16x32_bf16(pf[qt][0], vf0,
                                                                 oacc[qt][nd], 0, 0, 0);
          oacc[qt][nd] = __builtin_amdgcn_mfma_f32_16x16x32_bf16(pf[qt][1], vf1,
                                                                 oacc[qt][nd], 0, 0, 0);
        }
      }
    }
  }

  // --- epilogue: normalize and store [b][s][h][dh] ---
#pragma unroll
  for (int qt = 0; qt < 2; qt++) {
    float inv[4];
#pragma unroll
    for (int r = 0; r < 4; r++) inv[r] = 1.0f / lr[qt][r];
#pragma unroll
    for (int nd = 0; nd < 8; nd++)
#pragma unroll
      for (int r = 0; r < 4; r++) {
        int q = wq0 + qt * 16 + lkg * 4 + r;
        size_t idx = ((size_t)(b * S + q) * H + h) * DH + nd * 16 + lrow;
        attn_bf[idx] = f2bf(oacc[qt][nd][r] * inv[r]);
      }
  }
}

// ---------------- launch ----------------

extern "C" void kernel_launch(void* const* d_in, const int* in_sizes, int n_in,
                              void* d_out, int out_size, void* d_ws, size_t ws_size,
                              hipStream_t stream) {
  const float* x     = (const float*)d_in[0];
  const float* w_qkv = (const float*)d_in[1];
  const float* b_qkv = (const float*)d_in[2];
  const float* w_out = (const float*)d_in[3];
  const float* b_out = (const float*)d_in[4];
  float* out = (float*)d_out;

  char* ws = (char*)d_ws;
  u16* x_bf    = (u16*)ws; ws += (size_t)M * Dm * 2;
  u16* wqkvT   = (u16*)ws; ws += (size_t)N3 * Dm * 2;
  u16* woutT   = (u16*)ws; ws += (size_t)Dm * Dm * 2;
  u16* q_bf    = (u16*)ws; ws += (size_t)M * Dm * 2;
  u16* k_bf    = (u16*)ws; ws += (size_t)M * Dm * 2;
  u16* v_bfT   = (u16*)ws; ws += (size_t)M * Dm * 2;
  u16* attn_bf = (u16*)ws; ws += (size_t)M * Dm * 2;

  k_cvt_bf16<<<(M * Dm) / 1024, 256, 0, stream>>>(x, x_bf, M * Dm);
  k_transpose_bf16<<<dim3(N3 / 32, Dm / 32), 256, 0, stream>>>(w_qkv, wqkvT, Dm, N3);
  k_transpose_bf16<<<dim3(Dm / 32, Dm / 32), 256, 0, stream>>>(w_out, woutT, Dm, Dm);

  k_gemm<1><<<dim3(N3 / 128, M / 128), 256, 0, stream>>>(
      x_bf, wqkvT, b_qkv, out, q_bf, k_bf, v_bfT, Dm, N3);

  k_attn<<<dim3(S / 128, Bb * H), 256, 0, stream>>>(q_bf, k_bf, v_bfT, attn_bf);

  k_gemm<0><<<dim3(Dm / 128, M / 128), 256, 0, stream>>>(
      attn_bf, woutT, b_out, out, nullptr, nullptr, nullptr, Dm, Dm);
}

// Round 3
// 640.730 us; speedup vs baseline: 2.0876x; 1.2010x over previous
//
#include <hip/hip_runtime.h>
#include <hip/hip_bf16.h>
#include <cstdint>

typedef unsigned short u16;
typedef unsigned int u32;
typedef __attribute__((ext_vector_type(4))) float f32x4;
typedef __attribute__((ext_vector_type(8))) __bf16 bf16x8;

#define DEVFN static __device__ __forceinline__

constexpr int Bb = 4, S = 2048, Dm = 2048, H = 16, DH = 128;
constexpr int M  = Bb * S;   // 8192 rows
constexpr int N3 = 3 * Dm;   // 6144
constexpr float ATTN_SCALE = 0.088388347648318447f;  // 1/sqrt(128)
constexpr float LOG2E = 1.4426950408889634f;

DEVFN u16 f2bf(float f) {
  union { float f; u32 u; } v; v.f = f;
  u32 u = v.u;
  return (u16)((u + 0x7fffu + ((u >> 16) & 1u)) >> 16);
}

DEVFN void async16(const void* g, void* l) {
  __builtin_amdgcn_global_load_lds(
      (__attribute__((address_space(1))) unsigned int*)(g),
      (__attribute__((address_space(3))) unsigned int*)(l), 16, 0, 0);
}

// ---------------- prep kernels ----------------

__global__ __launch_bounds__(256) void k_cvt_bf16(const float* __restrict__ in,
                                                  u16* __restrict__ out, int n) {
  int i = (blockIdx.x * 256 + threadIdx.x) * 4;
  if (i < n) {
    float4 f = *(const float4*)(in + i);
    ushort4 o;
    o.x = f2bf(f.x); o.y = f2bf(f.y); o.z = f2bf(f.z); o.w = f2bf(f.w);
    *(ushort4*)(out + i) = o;
  }
}

// in: f32 [R][C] row-major -> out: bf16 [C][R] row-major
__global__ __launch_bounds__(256) void k_transpose_bf16(const float* __restrict__ in,
                                                        u16* __restrict__ out,
                                                        int R, int C) {
  __shared__ float tile[32][33];
  int c0 = blockIdx.x * 32, r0 = blockIdx.y * 32;
  int tx = threadIdx.x & 31, ty = threadIdx.x >> 5;  // 32 x 8
#pragma unroll
  for (int i = 0; i < 4; i++)
    tile[ty + 8 * i][tx] = in[(size_t)(r0 + ty + 8 * i) * C + c0 + tx];
  __syncthreads();
#pragma unroll
  for (int i = 0; i < 4; i++)
    out[(size_t)(c0 + ty + 8 * i) * R + r0 + tx] = f2bf(tile[tx][ty + 8 * i]);
}

// ---------------- 256x256 8-phase GEMM (HK-style, plain HIP) ----------------
// C = A[M,K](bf16) * BT[N,K](bf16)^T + bias. BK=64, 8 waves (2Mx4N).
// LDS: [buf][A|B][half][128 rows][64 k] bf16, XOR-swizzled (col^=(row&7)<<4),
// staged via global_load_lds with pre-swizzled SOURCE (linear LDS dest).

// region byte offsets inside the 128KiB LDS block
#define RA(buf, half) ((buf) * 65536 + (half) * 16384)
#define RB(buf, half) ((buf) * 65536 + 32768 + (half) * 16384)

DEVFN void stage_half(const u16* __restrict__ g, int grow0, int K, int vtile,
                      char* lds, int region, int tid) {
#pragma unroll
  for (int j = 0; j < 2; j++) {
    int L = j * 8192 + tid * 16;
    int row = L >> 7;
    int col = (((L & 127) ^ ((row & 7) << 4)) >> 1) + vtile * 64;
    async16(g + (size_t)(grow0 + row) * K + col,
            lds + region + j * 8192 + (tid & ~63) * 16);
  }
}

template <int BUF, int MSUB>
DEVFN void ldA(const char* lds, int wm, int lrow, int lkg, bf16x8 af[4][2]) {
#pragma unroll
  for (int mi = 0; mi < 4; mi++)
#pragma unroll
    for (int kk = 0; kk < 2; kk++) {
      int row = MSUB * 64 + mi * 16 + lrow;
      af[mi][kk] = *(const bf16x8*)(lds + RA(BUF, 0) + wm * 16384 + row * 128 +
                                    ((kk * 64 + lkg * 16) ^ ((row & 7) << 4)));
    }
}

template <int BUF, int NSUB>
DEVFN void ldB(const char* lds, int wn, int lrow, int lkg, bf16x8 bfr[2][2]) {
#pragma unroll
  for (int ni = 0; ni < 2; ni++)
#pragma unroll
    for (int kk = 0; kk < 2; kk++) {
      int row = (wn & 1) * 64 + NSUB * 32 + ni * 16 + lrow;
      bfr[ni][kk] = *(const bf16x8*)(lds + RB(BUF, 0) + (wn >> 1) * 16384 +
                                     row * 128 +
                                     ((kk * 64 + lkg * 16) ^ ((row & 7) << 4)));
    }
}

template <int MSUB, int NSUB>
DEVFN void mmq(f32x4 acc[8][4], bf16x8 af[4][2], bf16x8 bfr[2][2]) {
  __builtin_amdgcn_s_setprio(1);
#pragma unroll
  for (int kk = 0; kk < 2; kk++)
#pragma unroll
    for (int mi = 0; mi < 4; mi++)
#pragma unroll
      for (int ni = 0; ni < 2; ni++)
        acc[MSUB * 4 + mi][NSUB * 2 + ni] = __builtin_amdgcn_mfma_f32_16x16x32_bf16(
            af[mi][kk], bfr[ni][kk], acc[MSUB * 4 + mi][NSUB * 2 + ni], 0, 0, 0);
  __builtin_amdgcn_s_setprio(0);
}

#define BARRIER() __builtin_amdgcn_s_barrier()
#define LGK0() asm volatile("s_waitcnt lgkmcnt(0)" ::: "memory")
#define VM4() asm volatile("s_waitcnt vmcnt(4)" ::: "memory")

template <int MODE>
__global__ __launch_bounds__(512, 2) void k_gemm(
    const u16* __restrict__ A, const u16* __restrict__ BT,
    const float* __restrict__ bias, float* __restrict__ Cf,
    u16* __restrict__ q_bf, u16* __restrict__ k_bf, u16* __restrict__ v_bfT,
    int K, int N) {
  __shared__ __align__(16) char lds[131072];
  const int tid = threadIdx.x;
  const int wid = tid >> 6, lane = tid & 63;
  const int wm = wid >> 2, wn = wid & 3;
  const int lrow = lane & 15, lkg = lane >> 4;

  // XCD-aware bijective swizzle (gridDim.x % 8 == 0 for our shapes)
  const int nbx = N >> 8;
  const int cpx = gridDim.x >> 3;
  const int wg = (blockIdx.x & 7) * cpx + (blockIdx.x >> 3);
  const int tm0 = (wg / nbx) << 8, tn0 = (wg % nbx) << 8;

  const int NT = K >> 6;  // 64-wide K tiles

  f32x4 acc[8][4] = {};

  // ---- prologue: tile0 (A0,B0,A1,B1), tile1 (A0,B0) ----
  stage_half(A, tm0,       K, 0, lds, RA(0, 0), tid);
  stage_half(BT, tn0,      K, 0, lds, RB(0, 0), tid);
  stage_half(A, tm0 + 128, K, 0, lds, RA(0, 1), tid);
  stage_half(BT, tn0 + 128,K, 0, lds, RB(0, 1), tid);
  stage_half(A, tm0,       K, 1, lds, RA(1, 0), tid);
  stage_half(BT, tn0,      K, 1, lds, RB(1, 0), tid);
  VM4();
  BARRIER();

  for (int u = 0; u < NT; u += 2) {
    const int v2 = (u + 2 < NT) ? u + 2 : 0;  // clamped; lands in dead slots
    const int v3 = (u + 3 < NT) ? u + 3 : 0;
    bf16x8 af[4][2], b0[2][2], b1[2][2];

    // P1: read A-sub0 + B-sub0 of tile u; stage B1(u+1)
    ldA<0, 0>(lds, wm, lrow, lkg, af);
    ldB<0, 0>(lds, wn, lrow, lkg, b0);
    stage_half(BT, tn0 + 128, K, u + 1, lds, RB(1, 1), tid);
    BARRIER(); LGK0();
    mmq<0, 0>(acc, af, b0);
    BARRIER();

    // P2: read B-sub1(u); stage A1(u+1)
    ldB<0, 1>(lds, wn, lrow, lkg, b1);
    stage_half(A, tm0 + 128, K, u + 1, lds, RA(1, 1), tid);
    BARRIER(); LGK0();
    mmq<0, 1>(acc, af, b1);
    BARRIER();

    // P3: read A-sub1(u); stage B0(u+2)
    ldA<0, 1>(lds, wm, lrow, lkg, af);
    stage_half(BT, tn0, K, v2, lds, RB(0, 0), tid);
    BARRIER(); LGK0();
    mmq<1, 0>(acc, af, b0);
    BARRIER();

    // P4: stage A0(u+2); counted vmcnt
    stage_half(A, tm0, K, v2, lds, RA(0, 0), tid);
    VM4();
    BARRIER();
    mmq<1, 1>(acc, af, b1);
    BARRIER();

    // P5: read A-sub0 + B-sub0 of tile u+1; stage A1(u+2)
    ldA<1, 0>(lds, wm, lrow, lkg, af);
    ldB<1, 0>(lds, wn, lrow, lkg, b0);
    stage_half(A, tm0 + 128, K, v2, lds, RA(0, 1), tid);
    BARRIER(); LGK0();
    mmq<0, 0>(acc, af, b0);
    BARRIER();

    // P6: read B-sub1(u+1); stage B1(u+2)
    ldB<1, 1>(lds, wn, lrow, lkg, b1);
    stage_half(BT, tn0 + 128, K, v2, lds, RB(0, 1), tid);
    BARRIER(); LGK0();
    mmq<0, 1>(acc, af, b1);
    BARRIER();

    // P7: read A-sub1(u+1); stage B0(u+3)
    ldA<1, 1>(lds, wm, lrow, lkg, af);
    stage_half(BT, tn0, K, v3, lds, RB(1, 0), tid);
    BARRIER(); LGK0();
    mmq<1, 0>(acc, af, b0);
    BARRIER();

    // P8: stage A0(u+3); counted vmcnt
    stage_half(A, tm0, K, v3, lds, RA(1, 0), tid);
    VM4();
    BARRIER();
    mmq<1, 1>(acc, af, b1);
    BARRIER();
  }

  // ---- epilogue ----
  if (MODE == 0) {
#pragma unroll
    for (int mig = 0; mig < 8; mig++) {
      int row = tm0 + wm * 128 + (mig >> 2) * 64 + (mig & 3) * 16 + lkg * 4;
#pragma unroll
      for (int nig = 0; nig < 4; nig++) {
        int col = tn0 + wn * 64 + (nig >> 1) * 32 + (nig & 1) * 16 + lrow;
        float bv = bias[col];
#pragma unroll
        for (int r = 0; r < 4; r++)
          Cf[(size_t)(row + r) * N + col] = acc[mig][nig][r] + bv;
      }
    }
  } else {
#pragma unroll
    for (int mig = 0; mig < 8; mig++) {
      int row = tm0 + wm * 128 + (mig >> 2) * 64 + (mig & 3) * 16 + lkg * 4;
#pragma unroll
      for (int nig = 0; nig < 4; nig++) {
        int n = tn0 + wn * 64 + (nig >> 1) * 32 + (nig & 1) * 16 + lrow;
        float bv = bias[n];
        int type = n >> 11;      // 0:q 1:k 2:v
        int d = n & 2047;
        int h = d >> 7, dh = d & 127;
#pragma unroll
        for (int r = 0; r < 4; r++) {
          int rr = row + r;
          int b = rr >> 11, s = rr & 2047;
          float val = acc[mig][nig][r] + bv;
          size_t idx = ((size_t)(b * H + h) * S + s) * DH + dh;
          if (type == 0) {
            q_bf[idx] = f2bf(val * ATTN_SCALE);
          } else if (type == 1) {
            Cf[(size_t)M * Dm + idx] = val;      // k output (f32)
            k_bf[idx] = f2bf(val);
          } else {
            Cf[(size_t)2 * M * Dm + idx] = val;  // v output (f32)
            v_bfT[((size_t)(b * H + h) * DH + dh) * S + s] = f2bf(val);
          }
        }
      }
    }
  }
}

// ---------------- causal flash attention ----------------
// grid: (S/128, Bb*H); block = 4 waves, each wave owns 32 q-rows.
__global__ __launch_bounds__(256, 2) void k_attn(const u16* __restrict__ q_bf,
                                                 const u16* __restrict__ k_bf,
                                                 const u16* __restrict__ v_bfT,
                                                 u16* __restrict__ attn_bf) {
  __shared__ u16 ldsK[64 * 128];   // [k=64][d=128], 256B rows, swizzled
  __shared__ u16 ldsV[128 * 64];   // [d=128][k=64], 128B rows, swizzled
  __shared__ u16 ldsP[4][32 * 64]; // per-wave P tile [q=32][k=64], swizzled

  const int tid = threadIdx.x;
  const int wid = tid >> 6, lane = tid & 63;
  const int lrow = lane & 15, lkg = lane >> 4;
  const int bh = blockIdx.y;
  const int b = bh >> 4, h = bh & 15;
  const int qi = 15 - blockIdx.x;            // longest blocks dispatched first
  const int qb0 = qi * 128;
  const int wq0 = qb0 + wid * 32;
  const int swz = (lrow & 7) << 4;

  const u16* qp = q_bf + (size_t)bh * S * DH;
  const u16* kp = k_bf + (size_t)bh * S * DH;
  const u16* vp = v_bfT + (size_t)bh * DH * S;

  bf16x8 qf[2][4];
#pragma unroll
  for (int qt = 0; qt < 2; qt++)
#pragma unroll
    for (int kk = 0; kk < 4; kk++)
      qf[qt][kk] = *(const bf16x8*)(qp + (size_t)(wq0 + qt * 16 + lrow) * DH +
                                    kk * 32 + lkg * 8);

  float mr[2][4], lr[2][4];
#pragma unroll
  for (int qt = 0; qt < 2; qt++)
#pragma unroll
    for (int r = 0; r < 4; r++) { mr[qt][r] = -1e30f; lr[qt][r] = 0.f; }
  f32x4 oacc[2][8] = {};

  const int nkb = qi * 2 + 2;

  for (int kb = 0; kb < nkb; kb++) {
    __syncthreads();
#pragma unroll
    for (int i = 0; i < 4; i++) {
      int L = i * 4096 + wid * 1024 + lane * 16;
      int krow = L >> 8, kch = (L >> 4) & 15;
      async16(kp + (size_t)(kb * 64 + krow) * DH + ((kch ^ (krow & 7)) * 8),
              (char*)ldsK + L);
      int vd = L >> 7, vch = (L >> 4) & 7;
      async16(vp + (size_t)vd * S + kb * 64 + ((vch ^ (vd & 7)) * 8),
              (char*)ldsV + L);
    }
    __syncthreads();

    if (kb * 64 <= wq0 + 31) {
      f32x4 sacc[2][4] = {};
#pragma unroll
      for (int kt = 0; kt < 4; kt++)
#pragma unroll
        for (int kk = 0; kk < 4; kk++) {
          bf16x8 kf = *(const bf16x8*)((const char*)ldsK +
                        (kt * 16 + lrow) * 256 + ((kk * 64 + lkg * 16) ^ swz));
          sacc[0][kt] = __builtin_amdgcn_mfma_f32_16x16x32_bf16(qf[0][kk], kf,
                                                                sacc[0][kt], 0, 0, 0);
          sacc[1][kt] = __builtin_amdgcn_mfma_f32_16x16x32_bf16(qf[1][kk], kf,
                                                                sacc[1][kt], 0, 0, 0);
        }

      if (kb * 64 + 63 > wq0) {
#pragma unroll
        for (int qt = 0; qt < 2; qt++)
#pragma unroll
          for (int kt = 0; kt < 4; kt++) {
            int k = kb * 64 + kt * 16 + lrow;
#pragma unroll
            for (int r = 0; r < 4; r++)
              if (k > wq0 + qt * 16 + lkg * 4 + r) sacc[qt][kt][r] = -1e30f;
          }
      }

      float pm[2][4];
#pragma unroll
      for (int qt = 0; qt < 2; qt++)
#pragma unroll
        for (int r = 0; r < 4; r++)
          pm[qt][r] = fmaxf(fmaxf(sacc[qt][0][r], sacc[qt][1][r]),
                            fmaxf(sacc[qt][2][r], sacc[qt][3][r]));
#pragma unroll
      for (int off = 1; off < 16; off <<= 1)
#pragma unroll
        for (int qt = 0; qt < 2; qt++)
#pragma unroll
          for (int r = 0; r < 4; r++)
            pm[qt][r] = fmaxf(pm[qt][r], __shfl_xor(pm[qt][r], off, 64));

      float sc[2][4];
#pragma unroll
      for (int qt = 0; qt < 2; qt++)
#pragma unroll
        for (int r = 0; r < 4; r++) {
          float mn = fmaxf(mr[qt][r], pm[qt][r]);
          sc[qt][r] = exp2f((mr[qt][r] - mn) * LOG2E);
          mr[qt][r] = mn;
        }

      float rs[2][4] = {};
#pragma unroll
      for (int qt = 0; qt < 2; qt++)
#pragma unroll
        for (int kt = 0; kt < 4; kt++)
#pragma unroll
          for (int r = 0; r < 4; r++) {
            float p = exp2f((sacc[qt][kt][r] - mr[qt][r]) * LOG2E);
            rs[qt][r] += p;
            int prow = qt * 16 + lkg * 4 + r;
            *(u16*)((char*)ldsP[wid] + prow * 128 +
                    (((kt * 16 + lrow) * 2) ^ ((prow & 7) << 4))) = f2bf(p);
          }
#pragma unroll
      for (int off = 1; off < 16; off <<= 1)
#pragma unroll
        for (int qt = 0; qt < 2; qt++)
#pragma unroll
          for (int r = 0; r < 4; r++)
            rs[qt][r] += __shfl_xor(rs[qt][r], off, 64);
#pragma unroll
      for (int qt = 0; qt < 2; qt++)
#pragma unroll
        for (int r = 0; r < 4; r++)
          lr[qt][r] = lr[qt][r] * sc[qt][r] + rs[qt][r];
#pragma unroll
      for (int qt = 0; qt < 2; qt++)
#pragma unroll
        for (int nd = 0; nd < 8; nd++)
#pragma unroll
          for (int r = 0; r < 4; r++) oacc[qt][nd][r] *= sc[qt][r];

      asm volatile("s_waitcnt lgkmcnt(0)" ::: "memory");
      bf16x8 pf[2][2];
#pragma unroll
      for (int qt = 0; qt < 2; qt++)
#pragma unroll
        for (int kk = 0; kk < 2; kk++)
          pf[qt][kk] = *(const bf16x8*)((const char*)ldsP[wid] +
                         (qt * 16 + lrow) * 128 + ((kk * 64 + lkg * 16) ^ swz));
#pragma unroll
      for (int nd = 0; nd < 8; nd++) {
        bf16x8 vf0 = *(const bf16x8*)((const char*)ldsV +
                       (nd * 16 + lrow) * 128 + ((lkg * 16) ^ swz));
        bf16x8 vf1 = *(const bf16x8*)((const char*)ldsV +
                       (nd * 16 + lrow) * 128 + ((64 + lkg * 16) ^ swz));
#pragma unroll
        for (int qt = 0; qt < 2; qt++) {
          oacc[qt][nd] = __builtin_amdgcn_mfma_f32_16x16x32_bf16(pf[qt][0], vf0,
                                                                 oacc[qt][nd], 0, 0, 0);
          oacc[qt][nd] = __builtin_amdgcn_mfma_f32_16x16x32_bf16(pf[qt][1], vf1,
                                                                 oacc[qt][nd], 0, 0, 0);
        }
      }
    }
  }

#pragma unroll
  for (int qt = 0; qt < 2; qt++) {
    float inv[4];
#pragma unroll
    for (int r = 0; r < 4; r++) inv[r] = 1.0f / lr[qt][r];
#pragma unroll
    for (int nd = 0; nd < 8; nd++)
#pragma unroll
      for (int r = 0; r < 4; r++) {
        int q = wq0 + qt * 16 + lkg * 4 + r;
        size_t idx = ((size_t)(b * S + q) * H + h) * DH + nd * 16 + lrow;
        attn_bf[idx] = f2bf(oacc[qt][nd][r] * inv[r]);
      }
  }
}

// ---------------- launch ----------------

extern "C" void kernel_launch(void* const* d_in, const int* in_sizes, int n_in,
                              void* d_out, int out_size, void* d_ws, size_t ws_size,
                              hipStream_t stream) {
  const float* x     = (const float*)d_in[0];
  const float* w_qkv = (const float*)d_in[1];
  const float* b_qkv = (const float*)d_in[2];
  const float* w_out = (const float*)d_in[3];
  const float* b_out = (const float*)d_in[4];
  float* out = (float*)d_out;

  char* ws = (char*)d_ws;
  u16* x_bf    = (u16*)ws; ws += (size_t)M * Dm * 2;
  u16* wqkvT   = (u16*)ws; ws += (size_t)N3 * Dm * 2;
  u16* woutT   = (u16*)ws; ws += (size_t)Dm * Dm * 2;
  u16* q_bf    = (u16*)ws; ws += (size_t)M * Dm * 2;
  u16* k_bf    = (u16*)ws; ws += (size_t)M * Dm * 2;
  u16* v_bfT   = (u16*)ws; ws += (size_t)M * Dm * 2;
  u16* attn_bf = (u16*)ws; ws += (size_t)M * Dm * 2;

  k_cvt_bf16<<<(M * Dm) / 1024, 256, 0, stream>>>(x, x_bf, M * Dm);
  k_transpose_bf16<<<dim3(N3 / 32, Dm / 32), 256, 0, stream>>>(w_qkv, wqkvT, Dm, N3);
  k_transpose_bf16<<<dim3(Dm / 32, Dm / 32), 256, 0, stream>>>(w_out, woutT, Dm, Dm);

  k_gemm<1><<<(N3 / 256) * (M / 256), 512, 0, stream>>>(
      x_bf, wqkvT, b_qkv, out, q_bf, k_bf, v_bfT, Dm, N3);

  k_attn<<<dim3(S / 128, Bb * H), 256, 0, stream>>>(q_bf, k_bf, v_bfT, attn_bf);

  k_gemm<0><<<(Dm / 256) * (M / 256), 512, 0, stream>>>(
      attn_bf, woutT, b_out, out, nullptr, nullptr, nullptr, Dm, Dm);
}

// Round 4
// 601.597 us; speedup vs baseline: 2.2234x; 1.0650x over previous
//
#include <hip/hip_runtime.h>
#include <hip/hip_bf16.h>
#include <cstdint>

typedef unsigned short u16;
typedef unsigned int u32;
typedef __attribute__((ext_vector_type(4))) float f32x4;
typedef __attribute__((ext_vector_type(8))) __bf16 bf16x8;

#define DEVFN static __device__ __forceinline__

constexpr int Bb = 4, S = 2048, Dm = 2048, H = 16, DH = 128;
constexpr int M  = Bb * S;   // 8192 rows
constexpr int N3 = 3 * Dm;   // 6144
constexpr float ATTN_SCALE = 0.088388347648318447f;  // 1/sqrt(128)
constexpr float LOG2E = 1.4426950408889634f;

DEVFN u16 f2bf(float f) {
  union { float f; u32 u; } v; v.f = f;
  u32 u = v.u;
  return (u16)((u + 0x7fffu + ((u >> 16) & 1u)) >> 16);
}

DEVFN void async16(const void* g, void* l) {
  __builtin_amdgcn_global_load_lds(
      (__attribute__((address_space(1))) unsigned int*)(g),
      (__attribute__((address_space(3))) unsigned int*)(l), 16, 0, 0);
}

// ---------------- prep kernels ----------------

__global__ __launch_bounds__(256) void k_cvt_bf16(const float* __restrict__ in,
                                                  u16* __restrict__ out, int n) {
  int i = (blockIdx.x * 256 + threadIdx.x) * 4;
  if (i < n) {
    float4 f = *(const float4*)(in + i);
    ushort4 o;
    o.x = f2bf(f.x); o.y = f2bf(f.y); o.z = f2bf(f.z); o.w = f2bf(f.w);
    *(ushort4*)(out + i) = o;
  }
}

// in: f32 [R][C] row-major -> out: bf16 [C][R] row-major
__global__ __launch_bounds__(256) void k_transpose_bf16(const float* __restrict__ in,
                                                        u16* __restrict__ out,
                                                        int R, int C) {
  __shared__ float tile[32][33];
  int c0 = blockIdx.x * 32, r0 = blockIdx.y * 32;
  int tx = threadIdx.x & 31, ty = threadIdx.x >> 5;  // 32 x 8
#pragma unroll
  for (int i = 0; i < 4; i++)
    tile[ty + 8 * i][tx] = in[(size_t)(r0 + ty + 8 * i) * C + c0 + tx];
  __syncthreads();
#pragma unroll
  for (int i = 0; i < 4; i++)
    out[(size_t)(c0 + ty + 8 * i) * R + r0 + tx] = f2bf(tile[tx][ty + 8 * i]);
}

// ---------------- 256x256 8-phase GEMM (HK-style, plain HIP) ----------------

#define RA(buf, half) ((buf) * 65536 + (half) * 16384)
#define RB(buf, half) ((buf) * 65536 + 32768 + (half) * 16384)

DEVFN void stage_half(const u16* __restrict__ g, int grow0, int K, int vtile,
                      char* lds, int region, int tid) {
#pragma unroll
  for (int j = 0; j < 2; j++) {
    int L = j * 8192 + tid * 16;
    int row = L >> 7;
    int col = (((L & 127) ^ ((row & 7) << 4)) >> 1) + vtile * 64;
    async16(g + (size_t)(grow0 + row) * K + col,
            lds + region + j * 8192 + (tid & ~63) * 16);
  }
}

template <int BUF, int MSUB>
DEVFN void ldA(const char* lds, int wm, int lrow, int lkg, bf16x8 af[4][2]) {
#pragma unroll
  for (int mi = 0; mi < 4; mi++)
#pragma unroll
    for (int kk = 0; kk < 2; kk++) {
      int row = MSUB * 64 + mi * 16 + lrow;
      af[mi][kk] = *(const bf16x8*)(lds + RA(BUF, 0) + wm * 16384 + row * 128 +
                                    ((kk * 64 + lkg * 16) ^ ((row & 7) << 4)));
    }
}

template <int BUF, int NSUB>
DEVFN void ldB(const char* lds, int wn, int lrow, int lkg, bf16x8 bfr[2][2]) {
#pragma unroll
  for (int ni = 0; ni < 2; ni++)
#pragma unroll
    for (int kk = 0; kk < 2; kk++) {
      int row = (wn & 1) * 64 + NSUB * 32 + ni * 16 + lrow;
      bfr[ni][kk] = *(const bf16x8*)(lds + RB(BUF, 0) + (wn >> 1) * 16384 +
                                     row * 128 +
                                     ((kk * 64 + lkg * 16) ^ ((row & 7) << 4)));
    }
}

template <int MSUB, int NSUB>
DEVFN void mmq(f32x4 acc[8][4], bf16x8 af[4][2], bf16x8 bfr[2][2]) {
  __builtin_amdgcn_s_setprio(1);
#pragma unroll
  for (int kk = 0; kk < 2; kk++)
#pragma unroll
    for (int mi = 0; mi < 4; mi++)
#pragma unroll
      for (int ni = 0; ni < 2; ni++)
        acc[MSUB * 4 + mi][NSUB * 2 + ni] = __builtin_amdgcn_mfma_f32_16x16x32_bf16(
            af[mi][kk], bfr[ni][kk], acc[MSUB * 4 + mi][NSUB * 2 + ni], 0, 0, 0);
  __builtin_amdgcn_s_setprio(0);
}

#define BARRIER() __builtin_amdgcn_s_barrier()
#define LGK0() asm volatile("s_waitcnt lgkmcnt(0)" ::: "memory")
#define VM4() asm volatile("s_waitcnt vmcnt(4)" ::: "memory")

template <int MODE>
__global__ __launch_bounds__(512, 2) void k_gemm(
    const u16* __restrict__ A, const u16* __restrict__ BT,
    const float* __restrict__ bias, float* __restrict__ Cf,
    u16* __restrict__ q_bf, u16* __restrict__ k_bf, u16* __restrict__ v_bfT,
    int K, int N) {
  __shared__ __align__(16) char lds[131072];
  const int tid = threadIdx.x;
  const int wid = tid >> 6, lane = tid & 63;
  const int wm = wid >> 2, wn = wid & 3;
  const int lrow = lane & 15, lkg = lane >> 4;

  const int nbx = N >> 8;
  const int cpx = gridDim.x >> 3;
  const int wg = (blockIdx.x & 7) * cpx + (blockIdx.x >> 3);
  const int tm0 = (wg / nbx) << 8, tn0 = (wg % nbx) << 8;

  const int NT = K >> 6;

  f32x4 acc[8][4] = {};

  stage_half(A, tm0,       K, 0, lds, RA(0, 0), tid);
  stage_half(BT, tn0,      K, 0, lds, RB(0, 0), tid);
  stage_half(A, tm0 + 128, K, 0, lds, RA(0, 1), tid);
  stage_half(BT, tn0 + 128,K, 0, lds, RB(0, 1), tid);
  stage_half(A, tm0,       K, 1, lds, RA(1, 0), tid);
  stage_half(BT, tn0,      K, 1, lds, RB(1, 0), tid);
  VM4();
  BARRIER();

  for (int u = 0; u < NT; u += 2) {
    const int v2 = (u + 2 < NT) ? u + 2 : 0;
    const int v3 = (u + 3 < NT) ? u + 3 : 0;
    bf16x8 af[4][2], b0[2][2], b1[2][2];

    ldA<0, 0>(lds, wm, lrow, lkg, af);
    ldB<0, 0>(lds, wn, lrow, lkg, b0);
    stage_half(BT, tn0 + 128, K, u + 1, lds, RB(1, 1), tid);
    BARRIER(); LGK0();
    mmq<0, 0>(acc, af, b0);
    BARRIER();

    ldB<0, 1>(lds, wn, lrow, lkg, b1);
    stage_half(A, tm0 + 128, K, u + 1, lds, RA(1, 1), tid);
    BARRIER(); LGK0();
    mmq<0, 1>(acc, af, b1);
    BARRIER();

    ldA<0, 1>(lds, wm, lrow, lkg, af);
    stage_half(BT, tn0, K, v2, lds, RB(0, 0), tid);
    BARRIER(); LGK0();
    mmq<1, 0>(acc, af, b0);
    BARRIER();

    stage_half(A, tm0, K, v2, lds, RA(0, 0), tid);
    VM4();
    BARRIER();
    mmq<1, 1>(acc, af, b1);
    BARRIER();

    ldA<1, 0>(lds, wm, lrow, lkg, af);
    ldB<1, 0>(lds, wn, lrow, lkg, b0);
    stage_half(A, tm0 + 128, K, v2, lds, RA(0, 1), tid);
    BARRIER(); LGK0();
    mmq<0, 0>(acc, af, b0);
    BARRIER();

    ldB<1, 1>(lds, wn, lrow, lkg, b1);
    stage_half(BT, tn0 + 128, K, v2, lds, RB(0, 1), tid);
    BARRIER(); LGK0();
    mmq<0, 1>(acc, af, b1);
    BARRIER();

    ldA<1, 1>(lds, wm, lrow, lkg, af);
    stage_half(BT, tn0, K, v3, lds, RB(1, 0), tid);
    BARRIER(); LGK0();
    mmq<1, 0>(acc, af, b0);
    BARRIER();

    stage_half(A, tm0, K, v3, lds, RA(1, 0), tid);
    VM4();
    BARRIER();
    mmq<1, 1>(acc, af, b1);
    BARRIER();
  }

  if (MODE == 0) {
#pragma unroll
    for (int mig = 0; mig < 8; mig++) {
      int row = tm0 + wm * 128 + (mig >> 2) * 64 + (mig & 3) * 16 + lkg * 4;
#pragma unroll
      for (int nig = 0; nig < 4; nig++) {
        int col = tn0 + wn * 64 + (nig >> 1) * 32 + (nig & 1) * 16 + lrow;
        float bv = bias[col];
#pragma unroll
        for (int r = 0; r < 4; r++)
          Cf[(size_t)(row + r) * N + col] = acc[mig][nig][r] + bv;
      }
    }
  } else {
#pragma unroll
    for (int mig = 0; mig < 8; mig++) {
      int row = tm0 + wm * 128 + (mig >> 2) * 64 + (mig & 3) * 16 + lkg * 4;
#pragma unroll
      for (int nig = 0; nig < 4; nig++) {
        int n = tn0 + wn * 64 + (nig >> 1) * 32 + (nig & 1) * 16 + lrow;
        float bv = bias[n];
        int type = n >> 11;
        int d = n & 2047;
        int h = d >> 7, dh = d & 127;
#pragma unroll
        for (int r = 0; r < 4; r++) {
          int rr = row + r;
          int b = rr >> 11, s = rr & 2047;
          float val = acc[mig][nig][r] + bv;
          size_t idx = ((size_t)(b * H + h) * S + s) * DH + dh;
          if (type == 0) {
            q_bf[idx] = f2bf(val * ATTN_SCALE);
          } else if (type == 1) {
            Cf[(size_t)M * Dm + idx] = val;
            k_bf[idx] = f2bf(val);
          } else {
            Cf[(size_t)2 * M * Dm + idx] = val;
            v_bfT[((size_t)(b * H + h) * DH + dh) * S + s] = f2bf(val);
          }
        }
      }
    }
  }
}

// ---------------- causal flash attention v3 ----------------
// grid: (S/128, Bb*H); 4 waves x 32 q-rows. Double-buffered K/V staging:
// issue next tile's global_load_lds BEFORE computing current tile, single
// vmcnt(0)+barrier per iteration (T3-minimum). Defer-max (T13) skips the
// O-rescale when the running max doesn't grow by >8. setprio (T5) on MFMA.
__global__ __launch_bounds__(256, 2) void k_attn(const u16* __restrict__ q_bf,
                                                 const u16* __restrict__ k_bf,
                                                 const u16* __restrict__ v_bfT,
                                                 u16* __restrict__ attn_bf) {
  __shared__ u16 ldsK[2][64 * 128];   // [buf][k=64][d=128], swizzled
  __shared__ u16 ldsV[2][128 * 64];   // [buf][d=128][k=64], swizzled
  __shared__ u16 ldsP[4][32 * 64];    // per-wave P tile, swizzled  (80 KiB total)

  const int tid = threadIdx.x;
  const int wid = tid >> 6, lane = tid & 63;
  const int lrow = lane & 15, lkg = lane >> 4;
  const int bh = blockIdx.y;
  const int b = bh >> 4, h = bh & 15;
  const int qi = 15 - blockIdx.x;            // longest blocks dispatched first
  const int wq0 = qi * 128 + wid * 32;
  const int swz = (lrow & 7) << 4;

  const u16* qp = q_bf + (size_t)bh * S * DH;
  const u16* kp = k_bf + (size_t)bh * S * DH;
  const u16* vp = v_bfT + (size_t)bh * DH * S;

  bf16x8 qf[2][4];
#pragma unroll
  for (int qt = 0; qt < 2; qt++)
#pragma unroll
    for (int kk = 0; kk < 4; kk++)
      qf[qt][kk] = *(const bf16x8*)(qp + (size_t)(wq0 + qt * 16 + lrow) * DH +
                                    kk * 32 + lkg * 8);

  float mr[2][4], lr[2][4];
#pragma unroll
  for (int qt = 0; qt < 2; qt++)
#pragma unroll
    for (int r = 0; r < 4; r++) { mr[qt][r] = -1e30f; lr[qt][r] = 0.f; }
  f32x4 oacc[2][8] = {};

  const int nkb = qi * 2 + 2;

  // stage k-block kb into buffer buf
  auto stage = [&](int kb, int buf) {
#pragma unroll
    for (int i = 0; i < 4; i++) {
      int L = i * 4096 + wid * 1024 + lane * 16;
      int krow = L >> 8, kch = (L >> 4) & 15;
      async16(kp + (size_t)(kb * 64 + krow) * DH + ((kch ^ (krow & 7)) * 8),
              (char*)ldsK[buf] + L);
      int vd = L >> 7, vch = (L >> 4) & 7;
      async16(vp + (size_t)vd * S + kb * 64 + ((vch ^ (vd & 7)) * 8),
              (char*)ldsV[buf] + L);
    }
  };

  // prologue: stage tile 0 (also drains the Q loads)
  stage(0, 0);
  asm volatile("s_waitcnt vmcnt(0)" ::: "memory");
  __builtin_amdgcn_s_barrier();

  int cur = 0;
  for (int kb = 0; kb < nkb; kb++) {
    // issue next tile's loads first — they fly under this tile's compute
    if (kb + 1 < nkb) stage(kb + 1, cur ^ 1);

    if (kb * 64 <= wq0 + 31) {
      const u16* Kc = ldsK[cur];
      const u16* Vc = ldsV[cur];
      // --- QK^T: S[32q][64k] ---
      f32x4 sacc[2][4] = {};
      __builtin_amdgcn_s_setprio(1);
#pragma unroll
      for (int kt = 0; kt < 4; kt++)
#pragma unroll
        for (int kk = 0; kk < 4; kk++) {
          bf16x8 kf = *(const bf16x8*)((const char*)Kc +
                        (kt * 16 + lrow) * 256 + ((kk * 64 + lkg * 16) ^ swz));
          sacc[0][kt] = __builtin_amdgcn_mfma_f32_16x16x32_bf16(qf[0][kk], kf,
                                                                sacc[0][kt], 0, 0, 0);
          sacc[1][kt] = __builtin_amdgcn_mfma_f32_16x16x32_bf16(qf[1][kk], kf,
                                                                sacc[1][kt], 0, 0, 0);
        }
      __builtin_amdgcn_s_setprio(0);

      // --- causal mask (diagonal-straddling blocks only) ---
      if (kb * 64 + 63 > wq0) {
#pragma unroll
        for (int qt = 0; qt < 2; qt++)
#pragma unroll
          for (int kt = 0; kt < 4; kt++) {
            int k = kb * 64 + kt * 16 + lrow;
#pragma unroll
            for (int r = 0; r < 4; r++)
              if (k > wq0 + qt * 16 + lkg * 4 + r) sacc[qt][kt][r] = -1e30f;
          }
      }

      // --- row max of this tile ---
      float pm[2][4];
#pragma unroll
      for (int qt = 0; qt < 2; qt++)
#pragma unroll
        for (int r = 0; r < 4; r++)
          pm[qt][r] = fmaxf(fmaxf(sacc[qt][0][r], sacc[qt][1][r]),
                            fmaxf(sacc[qt][2][r], sacc[qt][3][r]));
#pragma unroll
      for (int off = 1; off < 16; off <<= 1)
#pragma unroll
        for (int qt = 0; qt < 2; qt++)
#pragma unroll
          for (int r = 0; r < 4; r++)
            pm[qt][r] = fmaxf(pm[qt][r], __shfl_xor(pm[qt][r], off, 64));

      // --- defer-max (T13): rescale only if max grew by > 8 ---
      float dmax = pm[0][0] - mr[0][0];
#pragma unroll
      for (int qt = 0; qt < 2; qt++)
#pragma unroll
        for (int r = 0; r < 4; r++)
          dmax = fmaxf(dmax, pm[qt][r] - mr[qt][r]);
      if (!__all(dmax <= 8.0f)) {
        float sc[2][4];
#pragma unroll
        for (int qt = 0; qt < 2; qt++)
#pragma unroll
          for (int r = 0; r < 4; r++) {
            float mn = fmaxf(mr[qt][r], pm[qt][r]);
            sc[qt][r] = exp2f((mr[qt][r] - mn) * LOG2E);
            mr[qt][r] = mn;
            lr[qt][r] *= sc[qt][r];
          }
#pragma unroll
        for (int qt = 0; qt < 2; qt++)
#pragma unroll
          for (int nd = 0; nd < 8; nd++)
#pragma unroll
            for (int r = 0; r < 4; r++) oacc[qt][nd][r] *= sc[qt][r];
      }

      // --- P = exp(S - mr); write bf16 P tile; row-sum ---
      float rs[2][4] = {};
#pragma unroll
      for (int qt = 0; qt < 2; qt++)
#pragma unroll
        for (int kt = 0; kt < 4; kt++)
#pragma unroll
          for (int r = 0; r < 4; r++) {
            float p = exp2f((sacc[qt][kt][r] - mr[qt][r]) * LOG2E);
            rs[qt][r] += p;
            int prow = qt * 16 + lkg * 4 + r;
            *(u16*)((char*)ldsP[wid] + prow * 128 +
                    (((kt * 16 + lrow) * 2) ^ ((prow & 7) << 4))) = f2bf(p);
          }
#pragma unroll
      for (int off = 1; off < 16; off <<= 1)
#pragma unroll
        for (int qt = 0; qt < 2; qt++)
#pragma unroll
          for (int r = 0; r < 4; r++)
            rs[qt][r] += __shfl_xor(rs[qt][r], off, 64);
#pragma unroll
      for (int qt = 0; qt < 2; qt++)
#pragma unroll
        for (int r = 0; r < 4; r++)
          lr[qt][r] += rs[qt][r];

      // --- PV: O += P[32q][64k] * V[64k][128d] ---
      asm volatile("s_waitcnt lgkmcnt(0)" ::: "memory");  // P write -> P read
      bf16x8 pf[2][2];
#pragma unroll
      for (int qt = 0; qt < 2; qt++)
#pragma unroll
        for (int kk = 0; kk < 2; kk++)
          pf[qt][kk] = *(const bf16x8*)((const char*)ldsP[wid] +
                         (qt * 16 + lrow) * 128 + ((kk * 64 + lkg * 16) ^ swz));
      __builtin_amdgcn_s_setprio(1);
#pragma unroll
      for (int nd = 0; nd < 8; nd++) {
        bf16x8 vf0 = *(const bf16x8*)((const char*)Vc +
                       (nd * 16 + lrow) * 128 + ((lkg * 16) ^ swz));
        bf16x8 vf1 = *(const bf16x8*)((const char*)Vc +
                       (nd * 16 + lrow) * 128 + ((64 + lkg * 16) ^ swz));
#pragma unroll
        for (int qt = 0; qt < 2; qt++) {
          oacc[qt][nd] = __builtin_amdgcn_mfma_f32_16x16x32_bf16(pf[qt][0], vf0,
                                                                 oacc[qt][nd], 0, 0, 0);
          oacc[qt][nd] = __builtin_amdgcn_mfma_f32_16x16x32_bf16(pf[qt][1], vf1,
                                                                 oacc[qt][nd], 0, 0, 0);
        }
      }
      __builtin_amdgcn_s_setprio(0);
    }

    // staged tile (kb+1) landed; all waves done reading buf[cur]
    asm volatile("s_waitcnt vmcnt(0)" ::: "memory");
    __builtin_amdgcn_s_barrier();
    cur ^= 1;
  }

  // --- epilogue: normalize and store [b][s][h][dh] ---
#pragma unroll
  for (int qt = 0; qt < 2; qt++) {
    float inv[4];
#pragma unroll
    for (int r = 0; r < 4; r++) inv[r] = 1.0f / lr[qt][r];
#pragma unroll
    for (int nd = 0; nd < 8; nd++)
#pragma unroll
      for (int r = 0; r < 4; r++) {
        int q = wq0 + qt * 16 + lkg * 4 + r;
        size_t idx = ((size_t)(b * S + q) * H + h) * DH + nd * 16 + lrow;
        attn_bf[idx] = f2bf(oacc[qt][nd][r] * inv[r]);
      }
  }
}

// ---------------- launch ----------------

extern "C" void kernel_launch(void* const* d_in, const int* in_sizes, int n_in,
                              void* d_out, int out_size, void* d_ws, size_t ws_size,
                              hipStream_t stream) {
  const float* x     = (const float*)d_in[0];
  const float* w_qkv = (const float*)d_in[1];
  const float* b_qkv = (const float*)d_in[2];
  const float* w_out = (const float*)d_in[3];
  const float* b_out = (const float*)d_in[4];
  float* out = (float*)d_out;

  char* ws = (char*)d_ws;
  u16* x_bf    = (u16*)ws; ws += (size_t)M * Dm * 2;
  u16* wqkvT   = (u16*)ws; ws += (size_t)N3 * Dm * 2;
  u16* woutT   = (u16*)ws; ws += (size_t)Dm * Dm * 2;
  u16* q_bf    = (u16*)ws; ws += (size_t)M * Dm * 2;
  u16* k_bf    = (u16*)ws; ws += (size_t)M * Dm * 2;
  u16* v_bfT   = (u16*)ws; ws += (size_t)M * Dm * 2;
  u16* attn_bf = (u16*)ws; ws += (size_t)M * Dm * 2;

  k_cvt_bf16<<<(M * Dm) / 1024, 256, 0, stream>>>(x, x_bf, M * Dm);
  k_transpose_bf16<<<dim3(N3 / 32, Dm / 32), 256, 0, stream>>>(w_qkv, wqkvT, Dm, N3);
  k_transpose_bf16<<<dim3(Dm / 32, Dm / 32), 256, 0, stream>>>(w_out, woutT, Dm, Dm);

  k_gemm<1><<<(N3 / 256) * (M / 256), 512, 0, stream>>>(
      x_bf, wqkvT, b_qkv, out, q_bf, k_bf, v_bfT, Dm, N3);

  k_attn<<<dim3(S / 128, Bb * H), 256, 0, stream>>>(q_bf, k_bf, v_bfT, attn_bf);

  k_gemm<0><<<(Dm / 256) * (M / 256), 512, 0, stream>>>(
      attn_bf, woutT, b_out, out, nullptr, nullptr, nullptr, Dm, Dm);
}

// Round 5
// 549.886 us; speedup vs baseline: 2.4325x; 1.0940x over previous
//
#include <hip/hip_runtime.h>
#include <hip/hip_bf16.h>
#include <cstdint>

typedef unsigned short u16;
typedef unsigned int u32;
typedef __attribute__((ext_vector_type(4))) float f32x4;
typedef __attribute__((ext_vector_type(8))) __bf16 bf16x8;

#define DEVFN static __device__ __forceinline__

constexpr int Bb = 4, S = 2048, Dm = 2048, H = 16, DH = 128;
constexpr int M  = Bb * S;   // 8192 rows
constexpr int N3 = 3 * Dm;   // 6144
constexpr float ATTN_SCALE = 0.088388347648318447f;  // 1/sqrt(128)
constexpr float LOG2E = 1.4426950408889634f;

DEVFN u16 f2bf(float f) {
  union { float f; u32 u; } v; v.f = f;
  u32 u = v.u;
  return (u16)((u + 0x7fffu + ((u >> 16) & 1u)) >> 16);
}

DEVFN void async16(const void* g, void* l) {
  __builtin_amdgcn_global_load_lds(
      (__attribute__((address_space(1))) unsigned int*)(g),
      (__attribute__((address_space(3))) unsigned int*)(l), 16, 0, 0);
}

// ---------------- prep kernels ----------------

__global__ __launch_bounds__(256) void k_cvt_bf16(const float* __restrict__ in,
                                                  u16* __restrict__ out, int n) {
  int i = (blockIdx.x * 256 + threadIdx.x) * 4;
  if (i < n) {
    float4 f = *(const float4*)(in + i);
    ushort4 o;
    o.x = f2bf(f.x); o.y = f2bf(f.y); o.z = f2bf(f.z); o.w = f2bf(f.w);
    *(ushort4*)(out + i) = o;
  }
}

// in: f32 [R][C] row-major -> out: bf16 [C][R] row-major
__global__ __launch_bounds__(256) void k_transpose_bf16(const float* __restrict__ in,
                                                        u16* __restrict__ out,
                                                        int R, int C) {
  __shared__ float tile[32][33];
  int c0 = blockIdx.x * 32, r0 = blockIdx.y * 32;
  int tx = threadIdx.x & 31, ty = threadIdx.x >> 5;  // 32 x 8
#pragma unroll
  for (int i = 0; i < 4; i++)
    tile[ty + 8 * i][tx] = in[(size_t)(r0 + ty + 8 * i) * C + c0 + tx];
  __syncthreads();
#pragma unroll
  for (int i = 0; i < 4; i++)
    out[(size_t)(c0 + ty + 8 * i) * R + r0 + tx] = f2bf(tile[tx][ty + 8 * i]);
}

// ---------------- 256x256 8-phase GEMM (HK-style, plain HIP) ----------------

#define RA(buf, half) ((buf) * 65536 + (half) * 16384)
#define RB(buf, half) ((buf) * 65536 + 32768 + (half) * 16384)

DEVFN void stage_half(const u16* __restrict__ g, int grow0, int K, int vtile,
                      char* lds, int region, int tid) {
#pragma unroll
  for (int j = 0; j < 2; j++) {
    int L = j * 8192 + tid * 16;
    int row = L >> 7;
    int col = (((L & 127) ^ ((row & 7) << 4)) >> 1) + vtile * 64;
    async16(g + (size_t)(grow0 + row) * K + col,
            lds + region + j * 8192 + (tid & ~63) * 16);
  }
}

template <int BUF, int MSUB>
DEVFN void ldA(const char* lds, int wm, int lrow, int lkg, bf16x8 af[4][2]) {
#pragma unroll
  for (int mi = 0; mi < 4; mi++)
#pragma unroll
    for (int kk = 0; kk < 2; kk++) {
      int row = MSUB * 64 + mi * 16 + lrow;
      af[mi][kk] = *(const bf16x8*)(lds + RA(BUF, 0) + wm * 16384 + row * 128 +
                                    ((kk * 64 + lkg * 16) ^ ((row & 7) << 4)));
    }
}

template <int BUF, int NSUB>
DEVFN void ldB(const char* lds, int wn, int lrow, int lkg, bf16x8 bfr[2][2]) {
#pragma unroll
  for (int ni = 0; ni < 2; ni++)
#pragma unroll
    for (int kk = 0; kk < 2; kk++) {
      int row = (wn & 1) * 64 + NSUB * 32 + ni * 16 + lrow;
      bfr[ni][kk] = *(const bf16x8*)(lds + RB(BUF, 0) + (wn >> 1) * 16384 +
                                     row * 128 +
                                     ((kk * 64 + lkg * 16) ^ ((row & 7) << 4)));
    }
}

template <int MSUB, int NSUB>
DEVFN void mmq(f32x4 acc[8][4], bf16x8 af[4][2], bf16x8 bfr[2][2]) {
  __builtin_amdgcn_s_setprio(1);
#pragma unroll
  for (int kk = 0; kk < 2; kk++)
#pragma unroll
    for (int mi = 0; mi < 4; mi++)
#pragma unroll
      for (int ni = 0; ni < 2; ni++)
        acc[MSUB * 4 + mi][NSUB * 2 + ni] = __builtin_amdgcn_mfma_f32_16x16x32_bf16(
            af[mi][kk], bfr[ni][kk], acc[MSUB * 4 + mi][NSUB * 2 + ni], 0, 0, 0);
  __builtin_amdgcn_s_setprio(0);
}

#define BARRIER() __builtin_amdgcn_s_barrier()
#define LGK0() asm volatile("s_waitcnt lgkmcnt(0)" ::: "memory")
#define VM4() asm volatile("s_waitcnt vmcnt(4)" ::: "memory")

template <int MODE>
__global__ __launch_bounds__(512, 2) void k_gemm(
    const u16* __restrict__ A, const u16* __restrict__ BT,
    const float* __restrict__ bias, float* __restrict__ Cf,
    u16* __restrict__ q_bf, u16* __restrict__ k_bf, u16* __restrict__ v_bfT,
    int K, int N) {
  __shared__ __align__(16) char lds[131072];
  const int tid = threadIdx.x;
  const int wid = tid >> 6, lane = tid & 63;
  const int wm = wid >> 2, wn = wid & 3;
  const int lrow = lane & 15, lkg = lane >> 4;

  // L2-blocked XCD mapping: XCD x owns tm-stripe [4x, 4x+4); within the
  // stripe, 4tm x 4tn rects swept tn-major. Concurrent 32 blocks/XCD then
  // touch 4 A-panels (4MB, L2-resident) + 8 B-panels (8MB sliding).
  const int bid = blockIdx.x;
  const int xcd = bid & 7;
  const int i = bid >> 3;        // [0, gridDim.x/8)
  const int r = i & 15;
  const int j = i >> 4;          // tn rect group
  const int tm0 = (xcd * 4 + (r >> 2)) << 8;
  const int tn0 = (j * 4 + (r & 3)) << 8;

  const int NT = K >> 6;

  f32x4 acc[8][4] = {};

  stage_half(A, tm0,       K, 0, lds, RA(0, 0), tid);
  stage_half(BT, tn0,      K, 0, lds, RB(0, 0), tid);
  stage_half(A, tm0 + 128, K, 0, lds, RA(0, 1), tid);
  stage_half(BT, tn0 + 128,K, 0, lds, RB(0, 1), tid);
  stage_half(A, tm0,       K, 1, lds, RA(1, 0), tid);
  stage_half(BT, tn0,      K, 1, lds, RB(1, 0), tid);
  VM4();
  BARRIER();

  for (int u = 0; u < NT; u += 2) {
    const int v2 = (u + 2 < NT) ? u + 2 : 0;
    const int v3 = (u + 3 < NT) ? u + 3 : 0;
    bf16x8 af[4][2], b0[2][2], b1[2][2];

    ldA<0, 0>(lds, wm, lrow, lkg, af);
    ldB<0, 0>(lds, wn, lrow, lkg, b0);
    stage_half(BT, tn0 + 128, K, u + 1, lds, RB(1, 1), tid);
    BARRIER(); LGK0();
    mmq<0, 0>(acc, af, b0);
    BARRIER();

    ldB<0, 1>(lds, wn, lrow, lkg, b1);
    stage_half(A, tm0 + 128, K, u + 1, lds, RA(1, 1), tid);
    BARRIER(); LGK0();
    mmq<0, 1>(acc, af, b1);
    BARRIER();

    ldA<0, 1>(lds, wm, lrow, lkg, af);
    stage_half(BT, tn0, K, v2, lds, RB(0, 0), tid);
    BARRIER(); LGK0();
    mmq<1, 0>(acc, af, b0);
    BARRIER();

    stage_half(A, tm0, K, v2, lds, RA(0, 0), tid);
    VM4();
    BARRIER();
    mmq<1, 1>(acc, af, b1);
    BARRIER();

    ldA<1, 0>(lds, wm, lrow, lkg, af);
    ldB<1, 0>(lds, wn, lrow, lkg, b0);
    stage_half(A, tm0 + 128, K, v2, lds, RA(0, 1), tid);
    BARRIER(); LGK0();
    mmq<0, 0>(acc, af, b0);
    BARRIER();

    ldB<1, 1>(lds, wn, lrow, lkg, b1);
    stage_half(BT, tn0 + 128, K, v2, lds, RB(0, 1), tid);
    BARRIER(); LGK0();
    mmq<0, 1>(acc, af, b1);
    BARRIER();

    ldA<1, 1>(lds, wm, lrow, lkg, af);
    stage_half(BT, tn0, K, v3, lds, RB(1, 0), tid);
    BARRIER(); LGK0();
    mmq<1, 0>(acc, af, b0);
    BARRIER();

    stage_half(A, tm0, K, v3, lds, RA(1, 0), tid);
    VM4();
    BARRIER();
    mmq<1, 1>(acc, af, b1);
    BARRIER();
  }

  if (MODE == 0) {
#pragma unroll
    for (int mig = 0; mig < 8; mig++) {
      int row = tm0 + wm * 128 + (mig >> 2) * 64 + (mig & 3) * 16 + lkg * 4;
#pragma unroll
      for (int nig = 0; nig < 4; nig++) {
        int col = tn0 + wn * 64 + (nig >> 1) * 32 + (nig & 1) * 16 + lrow;
        float bv = bias[col];
#pragma unroll
        for (int r2 = 0; r2 < 4; r2++)
          Cf[(size_t)(row + r2) * N + col] = acc[mig][nig][r2] + bv;
      }
    }
  } else {
#pragma unroll
    for (int mig = 0; mig < 8; mig++) {
      int row = tm0 + wm * 128 + (mig >> 2) * 64 + (mig & 3) * 16 + lkg * 4;
#pragma unroll
      for (int nig = 0; nig < 4; nig++) {
        int n = tn0 + wn * 64 + (nig >> 1) * 32 + (nig & 1) * 16 + lrow;
        float bv = bias[n];
        int type = n >> 11;
        int d = n & 2047;
        int h = d >> 7, dh = d & 127;
#pragma unroll
        for (int r2 = 0; r2 < 4; r2++) {
          int rr = row + r2;
          int b = rr >> 11, s = rr & 2047;
          float val = acc[mig][nig][r2] + bv;
          size_t idx = ((size_t)(b * H + h) * S + s) * DH + dh;
          if (type == 0) {
            q_bf[idx] = f2bf(val * ATTN_SCALE);
          } else if (type == 1) {
            Cf[(size_t)M * Dm + idx] = val;
            k_bf[idx] = f2bf(val);
          } else {
            Cf[(size_t)2 * M * Dm + idx] = val;
            v_bfT[((size_t)(b * H + h) * DH + dh) * S + s] = f2bf(val);
          }
        }
      }
    }
  }
}

// ---------------- causal flash attention v3 ----------------
// 1-D grid 1024; per-XCD bh clustering: each XCD owns 8 whole (b,h) groups so
// its concurrent blocks share 2MB of K/V (L2-resident). Longest-qi first.
// Double-buffered K/V staging (issue-before-compute), defer-max, setprio.
__global__ __launch_bounds__(256, 2) void k_attn(const u16* __restrict__ q_bf,
                                                 const u16* __restrict__ k_bf,
                                                 const u16* __restrict__ v_bfT,
                                                 u16* __restrict__ attn_bf) {
  __shared__ u16 ldsK[2][64 * 128];   // [buf][k=64][d=128], swizzled
  __shared__ u16 ldsV[2][128 * 64];   // [buf][d=128][k=64], swizzled
  __shared__ u16 ldsP[4][32 * 64];    // per-wave P tile, swizzled  (80 KiB total)

  const int tid = threadIdx.x;
  const int wid = tid >> 6, lane = tid & 63;
  const int lrow = lane & 15, lkg = lane >> 4;

  const int bid = blockIdx.x;          // grid = 1024
  const int xcd = bid & 7;
  const int ii = bid >> 3;             // [0,128) per XCD
  const int bh = xcd * 8 + (ii >> 4);  // 8 bh-groups per XCD
  const int qi = 15 - (ii & 15);       // longest blocks dispatched first
  const int b = bh >> 4, h = bh & 15;
  const int wq0 = qi * 128 + wid * 32;
  const int swz = (lrow & 7) << 4;

  const u16* qp = q_bf + (size_t)bh * S * DH;
  const u16* kp = k_bf + (size_t)bh * S * DH;
  const u16* vp = v_bfT + (size_t)bh * DH * S;

  bf16x8 qf[2][4];
#pragma unroll
  for (int qt = 0; qt < 2; qt++)
#pragma unroll
    for (int kk = 0; kk < 4; kk++)
      qf[qt][kk] = *(const bf16x8*)(qp + (size_t)(wq0 + qt * 16 + lrow) * DH +
                                    kk * 32 + lkg * 8);

  float mr[2][4], lr[2][4];
#pragma unroll
  for (int qt = 0; qt < 2; qt++)
#pragma unroll
    for (int r = 0; r < 4; r++) { mr[qt][r] = -1e30f; lr[qt][r] = 0.f; }
  f32x4 oacc[2][8] = {};

  const int nkb = qi * 2 + 2;

  auto stage = [&](int kb, int buf) {
#pragma unroll
    for (int i = 0; i < 4; i++) {
      int L = i * 4096 + wid * 1024 + lane * 16;
      int krow = L >> 8, kch = (L >> 4) & 15;
      async16(kp + (size_t)(kb * 64 + krow) * DH + ((kch ^ (krow & 7)) * 8),
              (char*)ldsK[buf] + L);
      int vd = L >> 7, vch = (L >> 4) & 7;
      async16(vp + (size_t)vd * S + kb * 64 + ((vch ^ (vd & 7)) * 8),
              (char*)ldsV[buf] + L);
    }
  };

  stage(0, 0);
  asm volatile("s_waitcnt vmcnt(0)" ::: "memory");
  __builtin_amdgcn_s_barrier();

  int cur = 0;
  for (int kb = 0; kb < nkb; kb++) {
    if (kb + 1 < nkb) stage(kb + 1, cur ^ 1);

    if (kb * 64 <= wq0 + 31) {
      const u16* Kc = ldsK[cur];
      const u16* Vc = ldsV[cur];
      f32x4 sacc[2][4] = {};
      __builtin_amdgcn_s_setprio(1);
#pragma unroll
      for (int kt = 0; kt < 4; kt++)
#pragma unroll
        for (int kk = 0; kk < 4; kk++) {
          bf16x8 kf = *(const bf16x8*)((const char*)Kc +
                        (kt * 16 + lrow) * 256 + ((kk * 64 + lkg * 16) ^ swz));
          sacc[0][kt] = __builtin_amdgcn_mfma_f32_16x16x32_bf16(qf[0][kk], kf,
                                                                sacc[0][kt], 0, 0, 0);
          sacc[1][kt] = __builtin_amdgcn_mfma_f32_16x16x32_bf16(qf[1][kk], kf,
                                                                sacc[1][kt], 0, 0, 0);
        }
      __builtin_amdgcn_s_setprio(0);

      if (kb * 64 + 63 > wq0) {
#pragma unroll
        for (int qt = 0; qt < 2; qt++)
#pragma unroll
          for (int kt = 0; kt < 4; kt++) {
            int k = kb * 64 + kt * 16 + lrow;
#pragma unroll
            for (int r = 0; r < 4; r++)
              if (k > wq0 + qt * 16 + lkg * 4 + r) sacc[qt][kt][r] = -1e30f;
          }
      }

      float pm[2][4];
#pragma unroll
      for (int qt = 0; qt < 2; qt++)
#pragma unroll
        for (int r = 0; r < 4; r++)
          pm[qt][r] = fmaxf(fmaxf(sacc[qt][0][r], sacc[qt][1][r]),
                            fmaxf(sacc[qt][2][r], sacc[qt][3][r]));
#pragma unroll
      for (int off = 1; off < 16; off <<= 1)
#pragma unroll
        for (int qt = 0; qt < 2; qt++)
#pragma unroll
          for (int r = 0; r < 4; r++)
            pm[qt][r] = fmaxf(pm[qt][r], __shfl_xor(pm[qt][r], off, 64));

      float dmax = pm[0][0] - mr[0][0];
#pragma unroll
      for (int qt = 0; qt < 2; qt++)
#pragma unroll
        for (int r = 0; r < 4; r++)
          dmax = fmaxf(dmax, pm[qt][r] - mr[qt][r]);
      if (!__all(dmax <= 8.0f)) {
        float sc[2][4];
#pragma unroll
        for (int qt = 0; qt < 2; qt++)
#pragma unroll
          for (int r = 0; r < 4; r++) {
            float mn = fmaxf(mr[qt][r], pm[qt][r]);
            sc[qt][r] = exp2f((mr[qt][r] - mn) * LOG2E);
            mr[qt][r] = mn;
            lr[qt][r] *= sc[qt][r];
          }
#pragma unroll
        for (int qt = 0; qt < 2; qt++)
#pragma unroll
          for (int nd = 0; nd < 8; nd++)
#pragma unroll
            for (int r = 0; r < 4; r++) oacc[qt][nd][r] *= sc[qt][r];
      }

      float rs[2][4] = {};
#pragma unroll
      for (int qt = 0; qt < 2; qt++)
#pragma unroll
        for (int kt = 0; kt < 4; kt++)
#pragma unroll
          for (int r = 0; r < 4; r++) {
            float p = exp2f((sacc[qt][kt][r] - mr[qt][r]) * LOG2E);
            rs[qt][r] += p;
            int prow = qt * 16 + lkg * 4 + r;
            *(u16*)((char*)ldsP[wid] + prow * 128 +
                    (((kt * 16 + lrow) * 2) ^ ((prow & 7) << 4))) = f2bf(p);
          }
#pragma unroll
      for (int off = 1; off < 16; off <<= 1)
#pragma unroll
        for (int qt = 0; qt < 2; qt++)
#pragma unroll
          for (int r = 0; r < 4; r++)
            rs[qt][r] += __shfl_xor(rs[qt][r], off, 64);
#pragma unroll
      for (int qt = 0; qt < 2; qt++)
#pragma unroll
        for (int r = 0; r < 4; r++)
          lr[qt][r] += rs[qt][r];

      asm volatile("s_waitcnt lgkmcnt(0)" ::: "memory");
      bf16x8 pf[2][2];
#pragma unroll
      for (int qt = 0; qt < 2; qt++)
#pragma unroll
        for (int kk = 0; kk < 2; kk++)
          pf[qt][kk] = *(const bf16x8*)((const char*)ldsP[wid] +
                         (qt * 16 + lrow) * 128 + ((kk * 64 + lkg * 16) ^ swz));
      __builtin_amdgcn_s_setprio(1);
#pragma unroll
      for (int nd = 0; nd < 8; nd++) {
        bf16x8 vf0 = *(const bf16x8*)((const char*)Vc +
                       (nd * 16 + lrow) * 128 + ((lkg * 16) ^ swz));
        bf16x8 vf1 = *(const bf16x8*)((const char*)Vc +
                       (nd * 16 + lrow) * 128 + ((64 + lkg * 16) ^ swz));
#pragma unroll
        for (int qt = 0; qt < 2; qt++) {
          oacc[qt][nd] = __builtin_amdgcn_mfma_f32_16x16x32_bf16(pf[qt][0], vf0,
                                                                 oacc[qt][nd], 0, 0, 0);
          oacc[qt][nd] = __builtin_amdgcn_mfma_f32_16x16x32_bf16(pf[qt][1], vf1,
                                                                 oacc[qt][nd], 0, 0, 0);
        }
      }
      __builtin_amdgcn_s_setprio(0);
    }

    asm volatile("s_waitcnt vmcnt(0)" ::: "memory");
    __builtin_amdgcn_s_barrier();
    cur ^= 1;
  }

#pragma unroll
  for (int qt = 0; qt < 2; qt++) {
    float inv[4];
#pragma unroll
    for (int r = 0; r < 4; r++) inv[r] = 1.0f / lr[qt][r];
#pragma unroll
    for (int nd = 0; nd < 8; nd++)
#pragma unroll
      for (int r = 0; r < 4; r++) {
        int q = wq0 + qt * 16 + lkg * 4 + r;
        size_t idx = ((size_t)(b * S + q) * H + h) * DH + nd * 16 + lrow;
        attn_bf[idx] = f2bf(oacc[qt][nd][r] * inv[r]);
      }
  }
}

// ---------------- launch ----------------

extern "C" void kernel_launch(void* const* d_in, const int* in_sizes, int n_in,
                              void* d_out, int out_size, void* d_ws, size_t ws_size,
                              hipStream_t stream) {
  const float* x     = (const float*)d_in[0];
  const float* w_qkv = (const float*)d_in[1];
  const float* b_qkv = (const float*)d_in[2];
  const float* w_out = (const float*)d_in[3];
  const float* b_out = (const float*)d_in[4];
  float* out = (float*)d_out;

  char* ws = (char*)d_ws;
  u16* x_bf    = (u16*)ws; ws += (size_t)M * Dm * 2;
  u16* wqkvT   = (u16*)ws; ws += (size_t)N3 * Dm * 2;
  u16* woutT   = (u16*)ws; ws += (size_t)Dm * Dm * 2;
  u16* q_bf    = (u16*)ws; ws += (size_t)M * Dm * 2;
  u16* k_bf    = (u16*)ws; ws += (size_t)M * Dm * 2;
  u16* v_bfT   = (u16*)ws; ws += (size_t)M * Dm * 2;
  u16* attn_bf = (u16*)ws; ws += (size_t)M * Dm * 2;

  k_cvt_bf16<<<(M * Dm) / 1024, 256, 0, stream>>>(x, x_bf, M * Dm);
  k_transpose_bf16<<<dim3(N3 / 32, Dm / 32), 256, 0, stream>>>(w_qkv, wqkvT, Dm, N3);
  k_transpose_bf16<<<dim3(Dm / 32, Dm / 32), 256, 0, stream>>>(w_out, woutT, Dm, Dm);

  k_gemm<1><<<(N3 / 256) * (M / 256), 512, 0, stream>>>(
      x_bf, wqkvT, b_qkv, out, q_bf, k_bf, v_bfT, Dm, N3);

  k_attn<<<S / 128 * Bb * H, 256, 0, stream>>>(q_bf, k_bf, v_bfT, attn_bf);

  k_gemm<0><<<(Dm / 256) * (M / 256), 512, 0, stream>>>(
      attn_bf, woutT, b_out, out, nullptr, nullptr, nullptr, Dm, Dm);
}